// Round 12
// baseline (60.299 us; speedup 1.0000x reference)
//
#include <hip/hip_runtime.h>

#define BN 8192
#define TN 512
#define HN 6
#define GN 24
#define CHUNK 32
#define WARM 12
#define NCH (TN / CHUNK)           // 16
#define NGRP ((WARM + CHUNK) / 4)  // 11 groups of 4 steps
#define WGRP (WARM / 4)            // 3 warm groups

typedef _Float16 half8 __attribute__((ext_vector_type(8)));
typedef _Float16 half2_t __attribute__((ext_vector_type(2)));
typedef float f32x16 __attribute__((ext_vector_type(16)));

__device__ __forceinline__ float fast_rcp(float x) { return __builtin_amdgcn_rcpf(x); }

// Exact Pade[7/6] tanh (rcp-based) — unbounded input squash only.
__device__ __forceinline__ float tanh_p(float x) {
    const float t = x * x;
    const float num = fmaf(fmaf(21.0f, t, 1260.0f), t, 10395.0f) * x;
    const float den = fmaf(fmaf((t + 210.0f), t, 4725.0f), t, 10395.0f);
    return num * fast_rcp(den);
}

// rcp-free odd deg-9 tanh for |x| <= ~1.7; err ~2.5e-4.
__device__ __forceinline__ float tanh_g(float x) {
    const float t = x * x;
    float p = fmaf(0.0028757f, t, -0.026650f);
    p = fmaf(p, t, 0.112441f);
    p = fmaf(p, t, -0.326964f);
    p = fmaf(p, t, 0.999661f);
    return x * p;
}

__device__ __forceinline__ unsigned packh2(_Float16 a, _Float16 b) {
    half2_t v; v.x = a; v.y = b;
    return __builtin_bit_cast(unsigned, v);
}

// squash 4 timesteps of raw input -> packed f16 pairs
__device__ __forceinline__ void squash_pack(const float4 rxa, const float4 rxc, const float4 ryv,
                                            unsigned m01[4], unsigned& m2a, unsigned& m2b) {
    const float i0[4] = {rxa.x, rxa.z, rxc.x, rxc.z};
    const float i1[4] = {rxa.y, rxa.w, rxc.y, rxc.w};
    const float i2[4] = {ryv.x, ryv.y, ryv.z, ryv.w};
    _Float16 s2h[4];
#pragma unroll
    for (int u = 0; u < 4; ++u) {
        const _Float16 q0 = (_Float16)tanh_p(0.5f * i0[u]);
        const _Float16 q1 = (_Float16)tanh_p(0.5f * i1[u]);
        s2h[u] = (_Float16)tanh_p(0.5f * i2[u]);
        m01[u] = packh2(q0, q1);
    }
    m2a = packh2(s2h[0], s2h[1]);
    m2b = packh2(s2h[2], s2h[3]);
}

// ---------------- prep: per-lane MFMA fragments ----------------
// A row r in 0..23: type = r&3 (i,f,g,o), cell = r>>2, orig gate = 6*type + cell.
// Row 24 = FC: 0.5*Wfc over the h K-slots (z lands in d[12] of lo lanes).
// K layout: k0..2 = s0..s2 (lo), k3..5 = h even (lo), k8..10 = h odd (hi), rest 0.
__global__ void prep_fold(const float* __restrict__ Wih, const float* __restrict__ Whh,
                          const float* __restrict__ bih, const float* __restrict__ bhh,
                          const float* __restrict__ Wfc, const float* __restrict__ bfc,
                          float* __restrict__ ws) {
    const int t    = threadIdx.x;   // 0..63 = lane id
    if (t >= 64) return;
    const int r    = t & 31;
    const int half = t >> 5;

    half8 av;
#pragma unroll
    for (int j = 0; j < 8; ++j) {
        const int kk = 8 * half + j;
        float v = 0.0f;
        if (r < GN) {
            const int type = r & 3, kc = r >> 2;
            const int orig = 6 * type + kc;
            const float sc = (type == 2) ? 1.0f : 0.5f;
            if (kk < 3)                    v = 2.0f * sc * Wih[orig * 3 + kk];
            else if (kk >= 3 && kk <= 5)   v = sc * Whh[orig * HN + 2 * (kk - 3)];      // h0,h2,h4
            else if (kk >= 8 && kk <= 10)  v = sc * Whh[orig * HN + 2 * (kk - 8) + 1];  // h1,h3,h5
        } else if (r == 24) {
            if (kk >= 3 && kk <= 5)        v = 0.5f * Wfc[2 * (kk - 3)];
            else if (kk >= 8 && kk <= 10)  v = 0.5f * Wfc[2 * (kk - 8) + 1];
        }
        av[j] = (_Float16)v;
    }
    ((half8*)ws)[t] = av;

    float* bb = ws + 256 + t * 16;
#pragma unroll
    for (int rr = 0; rr < 16; ++rr) {
        const int row = (rr & 3) + 8 * (rr >> 2) + 4 * half;
        float v = 0.0f;
        if (row < GN) {
            const int type = row & 3, kc = row >> 2;
            const int orig = 6 * type + kc;
            const float sc = (type == 2) ? 1.0f : 0.5f;
            v = sc * (bih[orig] + bhh[orig]);
        } else if (row == 24) {
            v = 0.5f * bfc[0];
        }
        bb[rr] = v;
    }

    float* wl = ws + 1280 + t * 4;
#pragma unroll
    for (int kk = 0; kk < 3; ++kk) wl[kk] = 0.5f * Wfc[2 * kk + half];
    wl[3] = 0.0f;

    if (t == 0) ws[1536] = 0.5f * bfc[0];
}

// ---------------- main: ILP2 streams/lane + software-pipelined squash ----------------
__global__ __launch_bounds__(256, 2)
void lstm6_mfma(const float* __restrict__ x,    // [B,T,2]
                const float* __restrict__ yp,   // [B,T,1]
                const float* __restrict__ ws,   // fragments from prep
                float* __restrict__ out)        // [B*T | B*6 | B*6]
{
    const int lane = threadIdx.x & 63;
    const int col  = lane & 31;
    const int hi   = lane >> 5;
    const int wid  = blockIdx.x * (blockDim.x >> 6) + (threadIdx.x >> 6);  // 0..2047

    const half8  afrag = ((const half8*)ws)[lane];
    const f32x16 cbias = ((const f32x16*)(ws + 256))[lane];
    const float4 wfcl  = ((const float4*)(ws + 1280))[lane];
    const float  bf    = ws[1536];

    const int chA = wid >> 8;                       // 0..7 (wave-uniform)
    const int b   = ((wid & 255) << 5) | col;       // same b for A and B
    const int tsA = chA * CHUNK;
    const int tsB = (chA + 8) * CHUNK;
    const int t0A = tsA - WARM;                     // -WARM for chA==0 (guarded)
    const int t0B = tsB - WARM;
    const bool skipA = (chA == 0);                  // A idle for g < WGRP

    const float* xb = x  + (size_t)b * (TN * 2);
    const float* yb = yp + (size_t)b * TN;
    float*       ob = out + (size_t)b * TN;

    // my squash window: lo lanes cover A, hi lanes cover B
    const int t0M = hi ? t0B : t0A;

    float hA[3] = {0, 0, 0}, cA[3] = {0, 0, 0};
    float hB[3] = {0, 0, 0}, cB[3] = {0, 0, 0};
    float rA0 = 0, rA1 = 0, rA2 = 0;
    float rB0 = 0, rB1 = 0, rB2 = 0;

    // ---- prologue: squash group 0; prefetch raw for group 1 ----
    int tL = t0M < 0 ? 0 : t0M;
    float4 ra = *reinterpret_cast<const float4*>(xb + 2 * tL);
    float4 rc = *reinterpret_cast<const float4*>(xb + 2 * tL + 4);
    float4 ry = *reinterpret_cast<const float4*>(yb + tL);

    unsigned cm01[4], cm2a, cm2b;
    squash_pack(ra, rc, ry, cm01, cm2a, cm2b);
    unsigned co01[4], co2a, co2b;
#pragma unroll
    for (int u = 0; u < 4; ++u) co01[u] = (unsigned)__shfl_xor((int)cm01[u], 32, 64);
    co2a = (unsigned)__shfl_xor((int)cm2a, 32, 64);
    co2b = (unsigned)__shfl_xor((int)cm2b, 32, 64);

    {
        int t1 = t0M + 4; if (t1 < 0) t1 = 0;
        ra = *reinterpret_cast<const float4*>(xb + 2 * t1);
        rc = *reinterpret_cast<const float4*>(xb + 2 * t1 + 4);
        ry = *reinterpret_cast<const float4*>(yb + t1);
    }

    for (int g = 0; g < NGRP; ++g) {
        // prefetch raw inputs for group g+2
        int tp = t0M + 4 * (g + 2 < NGRP ? g + 2 : NGRP - 1);
        if (tp < 0) tp = 0;
        const float4 la = *reinterpret_cast<const float4*>(xb + 2 * tp);
        const float4 lc = *reinterpret_cast<const float4*>(xb + 2 * tp + 4);
        const float4 ly = *reinterpret_cast<const float4*>(yb + tp);

        // squash group g+1 (from raw prefetched last iteration); shfl issued early
        unsigned tm01[4], tm2a, tm2b;
        squash_pack(ra, rc, ry, tm01, tm2a, tm2b);
        unsigned to01[4], to2a, to2b;
#pragma unroll
        for (int u = 0; u < 4; ++u) to01[u] = (unsigned)__shfl_xor((int)tm01[u], 32, 64);
        to2a = (unsigned)__shfl_xor((int)tm2a, 32, 64);
        to2b = (unsigned)__shfl_xor((int)tm2b, 32, 64);

        const bool aAct = !(skipA && g < WGRP);   // wave-uniform
        const bool rAct = (g >= WGRP);            // FC z needed from here
        const bool sAct = (g >= WGRP + 1);        // stores from here

#pragma unroll
        for (int u = 0; u < 4; ++u) {
            // ---------- stream A ----------
            if (aAct) {
                const _Float16 a0 = (_Float16)hA[0], a1 = (_Float16)hA[1], a2 = (_Float16)hA[2];
                const unsigned s2w = (u < 2) ? cm2a : cm2b;
                const unsigned s2s = (u & 1) ? (s2w >> 16) : (s2w & 0xffffu);
                const unsigned w0 = hi ? packh2(a0, a1) : cm01[u];
                const unsigned w1 = hi ? packh2(a2, (_Float16)0.0f)
                                       : (s2s | ((unsigned)__builtin_bit_cast(unsigned short, a0) << 16));
                const unsigned w2 = hi ? 0u : packh2(a1, a2);
                uint4 wb; wb.x = w0; wb.y = w1; wb.z = w2; wb.w = 0u;
                const f32x16 dA = __builtin_amdgcn_mfma_f32_32x32x16_f16(
                    afrag, __builtin_bit_cast(half8, wb), cbias, 0, 0, 0);

                if (u == 0) {
                    if (sAct && hi == 0) {
                        const float r3 = tanh_g(dA[12]);
                        *reinterpret_cast<float4*>(ob + (t0A + 4 * g) - 4) =
                            make_float4(rA0, rA1, rA2, r3);
                    }
                } else if (rAct) {
                    if      (u == 1) { rA0 = tanh_g(dA[12]); }
                    else if (u == 2) { rA1 = tanh_g(dA[12]); }
                    else             { rA2 = tanh_g(dA[12]); }
                }

#pragma unroll
                for (int kk = 0; kk < 3; ++kk) {
                    const float Ti = tanh_g(dA[4 * kk + 0]);
                    const float Tf = tanh_g(dA[4 * kk + 1]);
                    const float Tg = tanh_g(dA[4 * kk + 2]);
                    const float To = tanh_g(dA[4 * kk + 3]);
                    cA[kk] = 0.5f * (fmaf(Tf, cA[kk], cA[kk]) + fmaf(Ti, Tg, Tg));
                    const float Tc = tanh_g(cA[kk]);
                    hA[kk] = 0.5f * fmaf(To, Tc, Tc);
                }
            }

            // ---------- stream B (always active) ----------
            {
                const _Float16 b0 = (_Float16)hB[0], b1 = (_Float16)hB[1], b2 = (_Float16)hB[2];
                const unsigned s2w = (u < 2) ? co2a : co2b;
                const unsigned s2s = (u & 1) ? (s2w >> 16) : (s2w & 0xffffu);
                const unsigned w0 = hi ? packh2(b0, b1) : co01[u];
                const unsigned w1 = hi ? packh2(b2, (_Float16)0.0f)
                                       : (s2s | ((unsigned)__builtin_bit_cast(unsigned short, b0) << 16));
                const unsigned w2 = hi ? 0u : packh2(b1, b2);
                uint4 wb; wb.x = w0; wb.y = w1; wb.z = w2; wb.w = 0u;
                const f32x16 dB = __builtin_amdgcn_mfma_f32_32x32x16_f16(
                    afrag, __builtin_bit_cast(half8, wb), cbias, 0, 0, 0);

                if (u == 0) {
                    if (sAct && hi == 0) {
                        const float r3 = tanh_g(dB[12]);
                        *reinterpret_cast<float4*>(ob + (t0B + 4 * g) - 4) =
                            make_float4(rB0, rB1, rB2, r3);
                    }
                } else if (rAct) {
                    if      (u == 1) { rB0 = tanh_g(dB[12]); }
                    else if (u == 2) { rB1 = tanh_g(dB[12]); }
                    else             { rB2 = tanh_g(dB[12]); }
                }

#pragma unroll
                for (int kk = 0; kk < 3; ++kk) {
                    const float Ti = tanh_g(dB[4 * kk + 0]);
                    const float Tf = tanh_g(dB[4 * kk + 1]);
                    const float Tg = tanh_g(dB[4 * kk + 2]);
                    const float To = tanh_g(dB[4 * kk + 3]);
                    cB[kk] = 0.5f * (fmaf(Tf, cB[kk], cB[kk]) + fmaf(Ti, Tg, Tg));
                    const float Tc = tanh_g(cB[kk]);
                    hB[kk] = 0.5f * fmaf(To, Tc, Tc);
                }
            }
        }

        // rotate pipeline registers
#pragma unroll
        for (int u = 0; u < 4; ++u) { cm01[u] = tm01[u]; co01[u] = to01[u]; }
        cm2a = tm2a; cm2b = tm2b; co2a = to2a; co2b = to2b;
        ra = la; rc = lc; ry = ly;
    }

    // tails: last step's output from final h (f32 path, one shfl each)
    {
        float zp = hA[0] * wfcl.x;
        zp = fmaf(hA[1], wfcl.y, zp);
        zp = fmaf(hA[2], wfcl.z, zp);
        const float z = zp + __shfl_xor(zp, 32, 64) + bf;
        if (hi == 0)
            *reinterpret_cast<float4*>(ob + tsA + CHUNK - 4) = make_float4(rA0, rA1, rA2, tanh_g(z));
    }
    {
        float zp = hB[0] * wfcl.x;
        zp = fmaf(hB[1], wfcl.y, zp);
        zp = fmaf(hB[2], wfcl.z, zp);
        const float z = zp + __shfl_xor(zp, 32, 64) + bf;
        if (hi == 0)
            *reinterpret_cast<float4*>(ob + tsB + CHUNK - 4) = make_float4(rB0, rB1, rB2, tanh_g(z));
    }

    // final LSTM state comes from chunk 15 = stream B of waves with chA==7
    if (chA + 8 == NCH - 1) {
        float* ho = out + (size_t)BN * TN + (size_t)b * HN;
        float* co = ho + (size_t)BN * HN;
#pragma unroll
        for (int kk = 0; kk < 3; ++kk) {
            ho[2 * kk + hi] = hB[kk];
            co[2 * kk + hi] = cB[kk];
        }
    }
}

extern "C" void kernel_launch(void* const* d_in, const int* in_sizes, int n_in,
                              void* d_out, int out_size, void* d_ws, size_t ws_size,
                              hipStream_t stream) {
    const float* x   = (const float*)d_in[0];
    const float* yp  = (const float*)d_in[1];
    const float* Wih = (const float*)d_in[2];
    const float* Whh = (const float*)d_in[3];
    const float* bih = (const float*)d_in[4];
    const float* bhh = (const float*)d_in[5];
    const float* Wfc = (const float*)d_in[6];
    const float* bfc = (const float*)d_in[7];
    float* out = (float*)d_out;
    float* wsf = (float*)d_ws;   // 1537 floats

    prep_fold<<<1, 64, 0, stream>>>(Wih, Whh, bih, bhh, Wfc, bfc, wsf);

    const int nwaves  = (BN * NCH) / 32 / 2;   // 2048 (ILP2)
    const int nblocks = nwaves / 4;            // 512 (4 waves/block)
    lstm6_mfma<<<nblocks, 256, 0, stream>>>(x, yp, wsf, out);
}

// Round 13
// 56.933 us; speedup vs baseline: 1.0591x; 1.0591x over previous
//
#include <hip/hip_runtime.h>

#define BN 8192
#define TN 512
#define HN 6
#define GN 24
#define CHUNK 32
#define WARM 12
#define NCH (TN / CHUNK)           // 16
#define NGRP ((WARM + CHUNK) / 4)  // 11 groups of 4 steps
#define WGRP (WARM / 4)            // 3 warm groups

typedef _Float16 half8 __attribute__((ext_vector_type(8)));
typedef _Float16 half2_t __attribute__((ext_vector_type(2)));
typedef float f32x16 __attribute__((ext_vector_type(16)));

__device__ __forceinline__ float fast_rcp(float x) { return __builtin_amdgcn_rcpf(x); }

// Exact Pade[7/6] tanh (rcp-based) — unbounded input squash only.
__device__ __forceinline__ float tanh_p(float x) {
    const float t = x * x;
    const float num = fmaf(fmaf(21.0f, t, 1260.0f), t, 10395.0f) * x;
    const float den = fmaf(fmaf((t + 210.0f), t, 4725.0f), t, 10395.0f);
    return num * fast_rcp(den);
}

// rcp-free odd deg-9 tanh for |x| <= ~1.7; err ~2.5e-4.
__device__ __forceinline__ float tanh_g(float x) {
    const float t = x * x;
    float p = fmaf(0.0028757f, t, -0.026650f);
    p = fmaf(p, t, 0.112441f);
    p = fmaf(p, t, -0.326964f);
    p = fmaf(p, t, 0.999661f);
    return x * p;
}

__device__ __forceinline__ unsigned packh2(_Float16 a, _Float16 b) {
    half2_t v; v.x = a; v.y = b;
    return __builtin_bit_cast(unsigned, v);
}

// squash 4 timesteps of raw input -> packed f16 pairs
__device__ __forceinline__ void squash_pack(const float4 rxa, const float4 rxc, const float4 ryv,
                                            unsigned m01[4], unsigned& m2a, unsigned& m2b) {
    const float i0[4] = {rxa.x, rxa.z, rxc.x, rxc.z};
    const float i1[4] = {rxa.y, rxa.w, rxc.y, rxc.w};
    const float i2[4] = {ryv.x, ryv.y, ryv.z, ryv.w};
    _Float16 s2h[4];
#pragma unroll
    for (int u = 0; u < 4; ++u) {
        const _Float16 q0 = (_Float16)tanh_p(0.5f * i0[u]);
        const _Float16 q1 = (_Float16)tanh_p(0.5f * i1[u]);
        s2h[u] = (_Float16)tanh_p(0.5f * i2[u]);
        m01[u] = packh2(q0, q1);
    }
    m2a = packh2(s2h[0], s2h[1]);
    m2b = packh2(s2h[2], s2h[3]);
}

// ---------------- prep: per-lane MFMA fragments ----------------
// A row r in 0..23: type = r&3 (i,f,g,o), cell = r>>2, orig gate = 6*type + cell.
// Row 24 = FC: 0.5*Wfc over the h K-slots (z lands in d[12] of lo lanes).
// K layout: k0..2 = s0..s2 (lo), k3..5 = h even (lo), k8..10 = h odd (hi), rest 0.
__global__ void prep_fold(const float* __restrict__ Wih, const float* __restrict__ Whh,
                          const float* __restrict__ bih, const float* __restrict__ bhh,
                          const float* __restrict__ Wfc, const float* __restrict__ bfc,
                          float* __restrict__ ws) {
    const int t    = threadIdx.x;   // 0..63 = lane id
    if (t >= 64) return;
    const int r    = t & 31;
    const int half = t >> 5;

    half8 av;
#pragma unroll
    for (int j = 0; j < 8; ++j) {
        const int kk = 8 * half + j;
        float v = 0.0f;
        if (r < GN) {
            const int type = r & 3, kc = r >> 2;
            const int orig = 6 * type + kc;
            const float sc = (type == 2) ? 1.0f : 0.5f;
            if (kk < 3)                    v = 2.0f * sc * Wih[orig * 3 + kk];
            else if (kk >= 3 && kk <= 5)   v = sc * Whh[orig * HN + 2 * (kk - 3)];      // h0,h2,h4
            else if (kk >= 8 && kk <= 10)  v = sc * Whh[orig * HN + 2 * (kk - 8) + 1];  // h1,h3,h5
        } else if (r == 24) {
            if (kk >= 3 && kk <= 5)        v = 0.5f * Wfc[2 * (kk - 3)];
            else if (kk >= 8 && kk <= 10)  v = 0.5f * Wfc[2 * (kk - 8) + 1];
        }
        av[j] = (_Float16)v;
    }
    ((half8*)ws)[t] = av;

    float* bb = ws + 256 + t * 16;
#pragma unroll
    for (int rr = 0; rr < 16; ++rr) {
        const int row = (rr & 3) + 8 * (rr >> 2) + 4 * half;
        float v = 0.0f;
        if (row < GN) {
            const int type = row & 3, kc = row >> 2;
            const int orig = 6 * type + kc;
            const float sc = (type == 2) ? 1.0f : 0.5f;
            v = sc * (bih[orig] + bhh[orig]);
        } else if (row == 24) {
            v = 0.5f * bfc[0];
        }
        bb[rr] = v;
    }

    float* wl = ws + 1280 + t * 4;
#pragma unroll
    for (int kk = 0; kk < 3; ++kk) wl[kk] = 0.5f * Wfc[2 * kk + half];
    wl[3] = 0.0f;

    if (t == 0) ws[1536] = 0.5f * bfc[0];
}

// ---------------- main: ILP2, branch-free u-loop, pipelined squash ----------------
__global__ __launch_bounds__(256, 2)
void lstm6_mfma(const float* __restrict__ x,    // [B,T,2]
                const float* __restrict__ yp,   // [B,T,1]
                const float* __restrict__ ws,   // fragments from prep
                float* __restrict__ out)        // [B*T | B*6 | B*6]
{
    const int lane = threadIdx.x & 63;
    const int col  = lane & 31;
    const int hi   = lane >> 5;
    const int wid  = blockIdx.x * (blockDim.x >> 6) + (threadIdx.x >> 6);  // 0..2047

    const half8  afrag = ((const half8*)ws)[lane];
    const f32x16 cbias = ((const f32x16*)(ws + 256))[lane];
    const float4 wfcl  = ((const float4*)(ws + 1280))[lane];
    const float  bf    = ws[1536];

    const int chA = wid >> 8;                       // 0..7 (wave-uniform)
    const int b   = ((wid & 255) << 5) | col;       // same b for A and B
    const int tsA = chA * CHUNK;
    const int tsB = (chA + 8) * CHUNK;
    const int t0A = tsA - WARM;                     // -WARM for chA==0 (loads clamped)
    const int t0B = tsB - WARM;
    const bool skipA = (chA == 0);                  // A state reset at g==WGRP

    const float* xb = x  + (size_t)b * (TN * 2);
    const float* yb = yp + (size_t)b * TN;
    float*       ob = out + (size_t)b * TN;

    // my squash window: lo lanes cover A, hi lanes cover B
    const int t0M = hi ? t0B : t0A;

    float hA[3] = {0, 0, 0}, cA[3] = {0, 0, 0};
    float hB[3] = {0, 0, 0}, cB[3] = {0, 0, 0};
    float rA0 = 0, rA1 = 0, rA2 = 0;
    float rB0 = 0, rB1 = 0, rB2 = 0;

    // ---- prologue: squash group 0; prefetch raw for group 1 ----
    int tL = t0M < 0 ? 0 : t0M;
    float4 ra = *reinterpret_cast<const float4*>(xb + 2 * tL);
    float4 rc = *reinterpret_cast<const float4*>(xb + 2 * tL + 4);
    float4 ry = *reinterpret_cast<const float4*>(yb + tL);

    unsigned cm01[4], cm2a, cm2b;
    squash_pack(ra, rc, ry, cm01, cm2a, cm2b);
    unsigned co01[4], co2a, co2b;
#pragma unroll
    for (int u = 0; u < 4; ++u) co01[u] = (unsigned)__shfl_xor((int)cm01[u], 32, 64);
    co2a = (unsigned)__shfl_xor((int)cm2a, 32, 64);
    co2b = (unsigned)__shfl_xor((int)cm2b, 32, 64);

    {
        int t1 = t0M + 4; if (t1 < 0) t1 = 0;
        ra = *reinterpret_cast<const float4*>(xb + 2 * t1);
        rc = *reinterpret_cast<const float4*>(xb + 2 * t1 + 4);
        ry = *reinterpret_cast<const float4*>(yb + t1);
    }

    for (int g = 0; g < NGRP; ++g) {
        // chA==0: A ran garbage warm steps on clamped inputs; reset to the true
        // initial state exactly at the first real step (bit-identical to gating).
        if (skipA && g == WGRP) {
            hA[0] = hA[1] = hA[2] = 0.0f;
            cA[0] = cA[1] = cA[2] = 0.0f;
        }

        // prefetch raw inputs for group g+2
        int tp = t0M + 4 * (g + 2 < NGRP ? g + 2 : NGRP - 1);
        if (tp < 0) tp = 0;
        const float4 la = *reinterpret_cast<const float4*>(xb + 2 * tp);
        const float4 lc = *reinterpret_cast<const float4*>(xb + 2 * tp + 4);
        const float4 ly = *reinterpret_cast<const float4*>(yb + tp);

        // squash group g+1; shfl issued early (consumed next group)
        unsigned tm01[4], tm2a, tm2b;
        squash_pack(ra, rc, ry, tm01, tm2a, tm2b);
        unsigned to01[4], to2a, to2b;
#pragma unroll
        for (int u = 0; u < 4; ++u) to01[u] = (unsigned)__shfl_xor((int)tm01[u], 32, 64);
        to2a = (unsigned)__shfl_xor((int)tm2a, 32, 64);
        to2b = (unsigned)__shfl_xor((int)tm2b, 32, 64);

        const bool sAct = (g >= WGRP + 1);        // stores from here (uniform)

#pragma unroll
        for (int u = 0; u < 4; ++u) {
            // ---- build BOTH B-fragments first ----
            const _Float16 a0 = (_Float16)hA[0], a1 = (_Float16)hA[1], a2 = (_Float16)hA[2];
            const unsigned sAw = (u < 2) ? cm2a : cm2b;
            const unsigned sAs = (u & 1) ? (sAw >> 16) : (sAw & 0xffffu);
            const unsigned wA0 = hi ? packh2(a0, a1) : cm01[u];
            const unsigned wA1 = hi ? packh2(a2, (_Float16)0.0f)
                                    : (sAs | ((unsigned)__builtin_bit_cast(unsigned short, a0) << 16));
            const unsigned wA2 = hi ? 0u : packh2(a1, a2);
            uint4 wbA; wbA.x = wA0; wbA.y = wA1; wbA.z = wA2; wbA.w = 0u;

            const _Float16 b0 = (_Float16)hB[0], b1 = (_Float16)hB[1], b2 = (_Float16)hB[2];
            const unsigned sBw = (u < 2) ? co2a : co2b;
            const unsigned sBs = (u & 1) ? (sBw >> 16) : (sBw & 0xffffu);
            const unsigned wB0 = hi ? packh2(b0, b1) : co01[u];
            const unsigned wB1 = hi ? packh2(b2, (_Float16)0.0f)
                                    : (sBs | ((unsigned)__builtin_bit_cast(unsigned short, b0) << 16));
            const unsigned wB2 = hi ? 0u : packh2(b1, b2);
            uint4 wbB; wbB.x = wB0; wbB.y = wB1; wbB.z = wB2; wbB.w = 0u;

            // ---- issue both MFMAs back-to-back ----
            const f32x16 dA = __builtin_amdgcn_mfma_f32_32x32x16_f16(
                afrag, __builtin_bit_cast(half8, wbA), cbias, 0, 0, 0);
            const f32x16 dB = __builtin_amdgcn_mfma_f32_32x32x16_f16(
                afrag, __builtin_bit_cast(half8, wbB), cbias, 0, 0, 0);

            // ---- cell updates (chains for A and B interleave freely) ----
#pragma unroll
            for (int kk = 0; kk < 3; ++kk) {
                const float Ti = tanh_g(dA[4 * kk + 0]);
                const float Tf = tanh_g(dA[4 * kk + 1]);
                const float Tg = tanh_g(dA[4 * kk + 2]);
                const float To = tanh_g(dA[4 * kk + 3]);
                cA[kk] = 0.5f * (fmaf(Tf, cA[kk], cA[kk]) + fmaf(Ti, Tg, Tg));
                const float Tc = tanh_g(cA[kk]);
                hA[kk] = 0.5f * fmaf(To, Tc, Tc);
            }
#pragma unroll
            for (int kk = 0; kk < 3; ++kk) {
                const float Ti = tanh_g(dB[4 * kk + 0]);
                const float Tf = tanh_g(dB[4 * kk + 1]);
                const float Tg = tanh_g(dB[4 * kk + 2]);
                const float To = tanh_g(dB[4 * kk + 3]);
                cB[kk] = 0.5f * (fmaf(Tf, cB[kk], cB[kk]) + fmaf(Ti, Tg, Tg));
                const float Tc = tanh_g(cB[kk]);
                hB[kk] = 0.5f * fmaf(To, Tc, Tc);
            }

            // ---- FC output path (d[12] of lo lanes = z for step t+4g+u-1) ----
            if (u == 0) {
                if (sAct && hi == 0) {
                    const float r3A = tanh_g(dA[12]);
                    const float r3B = tanh_g(dB[12]);
                    *reinterpret_cast<float4*>(ob + (t0A + 4 * g) - 4) =
                        make_float4(rA0, rA1, rA2, r3A);
                    *reinterpret_cast<float4*>(ob + (t0B + 4 * g) - 4) =
                        make_float4(rB0, rB1, rB2, r3B);
                }
            } else if (u == 1) { rA0 = tanh_g(dA[12]); rB0 = tanh_g(dB[12]); }
            else if   (u == 2) { rA1 = tanh_g(dA[12]); rB1 = tanh_g(dB[12]); }
            else               { rA2 = tanh_g(dA[12]); rB2 = tanh_g(dB[12]); }
        }

        // rotate pipeline registers
#pragma unroll
        for (int u = 0; u < 4; ++u) { cm01[u] = tm01[u]; co01[u] = to01[u]; }
        cm2a = tm2a; cm2b = tm2b; co2a = to2a; co2b = to2b;
        ra = la; rc = lc; ry = ly;
    }

    // tails: last step's output from final h (f32 path, one shfl each)
    {
        float zp = hA[0] * wfcl.x;
        zp = fmaf(hA[1], wfcl.y, zp);
        zp = fmaf(hA[2], wfcl.z, zp);
        const float z = zp + __shfl_xor(zp, 32, 64) + bf;
        if (hi == 0)
            *reinterpret_cast<float4*>(ob + tsA + CHUNK - 4) = make_float4(rA0, rA1, rA2, tanh_g(z));
    }
    {
        float zp = hB[0] * wfcl.x;
        zp = fmaf(hB[1], wfcl.y, zp);
        zp = fmaf(hB[2], wfcl.z, zp);
        const float z = zp + __shfl_xor(zp, 32, 64) + bf;
        if (hi == 0)
            *reinterpret_cast<float4*>(ob + tsB + CHUNK - 4) = make_float4(rB0, rB1, rB2, tanh_g(z));
    }

    // final LSTM state comes from chunk 15 = stream B of waves with chA==7
    if (chA + 8 == NCH - 1) {
        float* ho = out + (size_t)BN * TN + (size_t)b * HN;
        float* co = ho + (size_t)BN * HN;
#pragma unroll
        for (int kk = 0; kk < 3; ++kk) {
            ho[2 * kk + hi] = hB[kk];
            co[2 * kk + hi] = cB[kk];
        }
    }
}

extern "C" void kernel_launch(void* const* d_in, const int* in_sizes, int n_in,
                              void* d_out, int out_size, void* d_ws, size_t ws_size,
                              hipStream_t stream) {
    const float* x   = (const float*)d_in[0];
    const float* yp  = (const float*)d_in[1];
    const float* Wih = (const float*)d_in[2];
    const float* Whh = (const float*)d_in[3];
    const float* bih = (const float*)d_in[4];
    const float* bhh = (const float*)d_in[5];
    const float* Wfc = (const float*)d_in[6];
    const float* bfc = (const float*)d_in[7];
    float* out = (float*)d_out;
    float* wsf = (float*)d_ws;   // 1537 floats

    prep_fold<<<1, 64, 0, stream>>>(Wih, Whh, bih, bhh, Wfc, bfc, wsf);

    const int nwaves  = (BN * NCH) / 32 / 2;   // 2048 (ILP2)
    const int nblocks = nwaves / 4;            // 512 (4 waves/block)
    lstm6_mfma<<<nblocks, 256, 0, stream>>>(x, yp, wsf, out);
}